// Round 6
// baseline (518.941 us; speedup 1.0000x reference)
//
#include <hip/hip_runtime.h>
#include <hip/hip_bf16.h>
#include <stdint.h>

#define NW   1024
#define D    768
#define NS   8192
#define MAXW 30
#define FFNN 1000
#define FEAT 20

typedef __attribute__((ext_vector_type(8))) short bf16x8;
typedef __attribute__((ext_vector_type(4))) float f32x4;
#define MFMA16 __builtin_amdgcn_mfma_f32_16x16x32_bf16

// ws layout (float-slot offsets)
#define O_P    0                          // 3*1024*1000 fp32 P1,P2,P3
#define O_P4   3072000                    // 30*1000
#define O_HS   3102000                    // 1024
#define O_ATT  3103024                    // 8192*32
#define O_PS   3365168                    // 8192*16
#define O_ORD  3496240                    // (unused now)
#define O_H1R  3504432                    // H1 hi/lo bf16; later pk[8192] u64

__device__ inline ushort f2b(float v) {
    __hip_bfloat16 b = __float2bfloat16(v);
    return *(ushort*)&b;
}
__device__ inline float b2f(ushort u) {
    __hip_bfloat16 b = *(__hip_bfloat16*)&u;
    return __bfloat162float(b);
}

// ---------- head scores ----------
__global__ __launch_bounds__(256) void k_head(const float* __restrict__ doc,
                                              const float* __restrict__ wh,
                                              const float* __restrict__ bh,
                                              float* __restrict__ hs) {
    int wid = threadIdx.x >> 6, lane = threadIdx.x & 63;
    int word = blockIdx.x * 4 + wid;
    const float* row = doc + word * D;
    float acc = 0.f;
    for (int d = lane; d < D; d += 64) acc += row[d] * wh[d];
    #pragma unroll
    for (int o = 32; o; o >>= 1) acc += __shfl_down(acc, o);
    if (lane == 0) hs[word] = acc + bh[0];
}

// ---------- P4 = w_width_emb @ W1[1536:1556,:] ----------
__global__ __launch_bounds__(256) void k_p4(const float* __restrict__ wwe,
                                            const float* __restrict__ W1,
                                            float* __restrict__ P4) {
    int o = blockIdx.x * 256 + threadIdx.x;
    if (o >= 30 * FFNN) return;
    int wi = o / FFNN, j = o - wi * FFNN;
    float acc = 0.f;
    #pragma unroll
    for (int f = 0; f < FEAT; ++f) acc += wwe[wi * FEAT + f] * W1[(1536 + f) * FFNN + j];
    P4[o] = acc;
}

// ---------- split fp32 -> bf16 hi/lo ----------
__global__ __launch_bounds__(256) void k_split(const float* __restrict__ src,
                                               ushort* __restrict__ h,
                                               ushort* __restrict__ l, int n) {
    int i = blockIdx.x * 256 + threadIdx.x;
    if (i >= n) return;
    float v = src[i];
    ushort hi = f2b(v);
    float r = v - b2f(hi);
    h[i] = hi;
    l[i] = f2b(r);
}

// ---------- W1 slices: transpose + split -> W1T[z][1024 n][768 k] hi/lo ----------
__global__ void k_tw1(const float* __restrict__ W1,
                      ushort* __restrict__ TH, ushort* __restrict__ TL) {
    __shared__ float tile[32][33];
    int tx = threadIdx.x, ty = threadIdx.y;
    int k0 = blockIdx.x * 32, n0 = blockIdx.y * 32, z = blockIdx.z;
    int roff = (z == 0) ? 0 : (z == 1) ? 768 : 1556;
    #pragma unroll
    for (int i = 0; i < 4; ++i) {
        int kk = ty + i * 8;
        float v = (n0 + tx < FFNN) ? W1[(size_t)(roff + k0 + kk) * FFNN + n0 + tx] : 0.f;
        tile[kk][tx] = v;
    }
    __syncthreads();
    #pragma unroll
    for (int i = 0; i < 4; ++i) {
        int nn = ty + i * 8;
        float v = tile[tx][nn];
        ushort hi = f2b(v);
        float r = v - b2f(hi);
        size_t o = (size_t)z * 1024 * D + (size_t)(n0 + nn) * D + k0 + tx;
        TH[o] = hi;
        TL[o] = f2b(r);
    }
}

// ---------- W2: transpose + split -> W2T[1024 n][1000 k] hi/lo ----------
__global__ void k_tw2(const float* __restrict__ W2,
                      ushort* __restrict__ TH, ushort* __restrict__ TL) {
    __shared__ float tile[32][33];
    int tx = threadIdx.x, ty = threadIdx.y;
    int k0 = blockIdx.x * 32, n0 = blockIdx.y * 32;
    #pragma unroll
    for (int i = 0; i < 4; ++i) {
        int kk = ty + i * 8;
        float v = (k0 + kk < FFNN && n0 + tx < FFNN)
                    ? W2[(size_t)(k0 + kk) * FFNN + n0 + tx] : 0.f;
        tile[kk][tx] = v;
    }
    __syncthreads();
    #pragma unroll
    for (int i = 0; i < 4; ++i) {
        int nn = ty + i * 8;
        int k = k0 + tx;
        if (k < FFNN) {
            float v = tile[tx][nn];
            ushort hi = f2b(v);
            float r = v - b2f(hi);
            size_t o = (size_t)(n0 + nn) * FFNN + k;
            TH[o] = hi;
            TL[o] = f2b(r);
        }
    }
}

// ---------- MFMA GEMM: P[z] = doc @ W1slice  (split-bf16 3-term, 128x128 tile) ----------
__global__ __launch_bounds__(256) void k_gemmPm(const ushort* __restrict__ Ah_g,
                                                const ushort* __restrict__ Al_g,
                                                const ushort* __restrict__ Bh_g,
                                                const ushort* __restrict__ Bl_g,
                                                float* __restrict__ Pout) {
    __shared__ ushort Ah[128][40], Al[128][40], Bh[128][40], Bl[128][40];
    int tid = threadIdx.x;
    int row0 = blockIdx.y * 128, col0 = blockIdx.x * 128;
    size_t zoff = (size_t)blockIdx.z * 1024 * D;
    const ushort* Bh_z = Bh_g + zoff;
    const ushort* Bl_z = Bl_g + zoff;
    float* C = Pout + (size_t)blockIdx.z * NW * FFNN;
    int w = tid >> 6, l = tid & 63;
    int wr = w >> 1, wc = w & 1;
    int fr = l & 15, kb = l >> 4;
    f32x4 acc[4][4] = {};
    for (int kt = 0; kt < D; kt += 32) {
        #pragma unroll
        for (int i = 0; i < 2; ++i) {
            int cid = tid + i * 256;
            int r = cid >> 2, kc = cid & 3;
            int kg = kt + kc * 8;
            uint4 a0 = *(const uint4*)(Ah_g + (size_t)(row0 + r) * D + kg);
            uint4 a1 = *(const uint4*)(Al_g + (size_t)(row0 + r) * D + kg);
            uint4 b0 = *(const uint4*)(Bh_z + (size_t)(col0 + r) * D + kg);
            uint4 b1 = *(const uint4*)(Bl_z + (size_t)(col0 + r) * D + kg);
            *(uint4*)&Ah[r][kc * 8] = a0;
            *(uint4*)&Al[r][kc * 8] = a1;
            *(uint4*)&Bh[r][kc * 8] = b0;
            *(uint4*)&Bl[r][kc * 8] = b1;
        }
        __syncthreads();
        bf16x8 af[4], alf[4], bfr[4], blf[4];
        #pragma unroll
        for (int mt = 0; mt < 4; ++mt) {
            int r = wr * 64 + mt * 16 + fr;
            af[mt]  = *(const bf16x8*)&Ah[r][kb * 8];
            alf[mt] = *(const bf16x8*)&Al[r][kb * 8];
        }
        #pragma unroll
        for (int nt = 0; nt < 4; ++nt) {
            int c = wc * 64 + nt * 16 + fr;
            bfr[nt] = *(const bf16x8*)&Bh[c][kb * 8];
            blf[nt] = *(const bf16x8*)&Bl[c][kb * 8];
        }
        #pragma unroll
        for (int mt = 0; mt < 4; ++mt)
            #pragma unroll
            for (int nt = 0; nt < 4; ++nt) {
                acc[mt][nt] = MFMA16(af[mt], bfr[nt], acc[mt][nt], 0, 0, 0);
                acc[mt][nt] = MFMA16(af[mt], blf[nt], acc[mt][nt], 0, 0, 0);
                acc[mt][nt] = MFMA16(alf[mt], bfr[nt], acc[mt][nt], 0, 0, 0);
            }
        __syncthreads();
    }
    #pragma unroll
    for (int mt = 0; mt < 4; ++mt)
        #pragma unroll
        for (int nt = 0; nt < 4; ++nt)
            #pragma unroll
            for (int r = 0; r < 4; ++r) {
                int row = row0 + wr * 64 + mt * 16 + kb * 4 + r;
                int col = col0 + wc * 64 + nt * 16 + fr;
                if (col < FFNN) C[(size_t)row * FFNN + col] = acc[mt][nt][r];
            }
}

// ---------- MFMA GEMM2 fused: relu(H1@W2+b2).W3 -> PS  (split-bf16, 128x128) ----------
__global__ __launch_bounds__(256) void k_gemm2m(const ushort* __restrict__ Ah_g,
                                                const ushort* __restrict__ Al_g,
                                                const ushort* __restrict__ Bh_g,
                                                const ushort* __restrict__ Bl_g,
                                                const float* __restrict__ b2,
                                                const float* __restrict__ W3,
                                                float* __restrict__ PS) {
    __shared__ ushort Ah[128][40], Al[128][40], Bh[128][40], Bl[128][40];
    int tid = threadIdx.x;
    int row0 = blockIdx.y * 128, col0 = blockIdx.x * 128;
    int w = tid >> 6, l = tid & 63;
    int wr = w >> 1, wc = w & 1;
    int fr = l & 15, kb = l >> 4;
    f32x4 acc[4][4] = {};
    for (int kt = 0; kt < FFNN; kt += 32) {
        #pragma unroll
        for (int i = 0; i < 2; ++i) {
            int cid = tid + i * 256;
            int r = cid >> 2, kc = cid & 3;
            int kg = kt + kc * 8;
            bool v = (kg + 7) < FFNN;
            uint4 z = make_uint4(0, 0, 0, 0);
            uint4 a0 = v ? *(const uint4*)(Ah_g + (size_t)(row0 + r) * FFNN + kg) : z;
            uint4 a1 = v ? *(const uint4*)(Al_g + (size_t)(row0 + r) * FFNN + kg) : z;
            uint4 b0 = v ? *(const uint4*)(Bh_g + (size_t)(col0 + r) * FFNN + kg) : z;
            uint4 b1 = v ? *(const uint4*)(Bl_g + (size_t)(col0 + r) * FFNN + kg) : z;
            *(uint4*)&Ah[r][kc * 8] = a0;
            *(uint4*)&Al[r][kc * 8] = a1;
            *(uint4*)&Bh[r][kc * 8] = b0;
            *(uint4*)&Bl[r][kc * 8] = b1;
        }
        __syncthreads();
        bf16x8 af[4], alf[4], bfr[4], blf[4];
        #pragma unroll
        for (int mt = 0; mt < 4; ++mt) {
            int r = wr * 64 + mt * 16 + fr;
            af[mt]  = *(const bf16x8*)&Ah[r][kb * 8];
            alf[mt] = *(const bf16x8*)&Al[r][kb * 8];
        }
        #pragma unroll
        for (int nt = 0; nt < 4; ++nt) {
            int c = wc * 64 + nt * 16 + fr;
            bfr[nt] = *(const bf16x8*)&Bh[c][kb * 8];
            blf[nt] = *(const bf16x8*)&Bl[c][kb * 8];
        }
        #pragma unroll
        for (int mt = 0; mt < 4; ++mt)
            #pragma unroll
            for (int nt = 0; nt < 4; ++nt) {
                acc[mt][nt] = MFMA16(af[mt], bfr[nt], acc[mt][nt], 0, 0, 0);
                acc[mt][nt] = MFMA16(af[mt], blf[nt], acc[mt][nt], 0, 0, 0);
                acc[mt][nt] = MFMA16(alf[mt], bfr[nt], acc[mt][nt], 0, 0, 0);
            }
        __syncthreads();
    }
    float w3v[4], b2v[4];
    #pragma unroll
    for (int nt = 0; nt < 4; ++nt) {
        int col = col0 + wc * 64 + nt * 16 + fr;
        bool cv = col < FFNN;
        w3v[nt] = cv ? W3[col] : 0.f;
        b2v[nt] = cv ? b2[col] : 0.f;
    }
    #pragma unroll
    for (int mt = 0; mt < 4; ++mt) {
        #pragma unroll
        for (int r = 0; r < 4; ++r) {
            float p = 0.f;
            #pragma unroll
            for (int nt = 0; nt < 4; ++nt) {
                float v = fmaxf(acc[mt][nt][r] + b2v[nt], 0.f);
                p = fmaf(v, w3v[nt], p);
            }
            p += __shfl_xor(p, 1);
            p += __shfl_xor(p, 2);
            p += __shfl_xor(p, 4);
            p += __shfl_xor(p, 8);
            if (fr == 0) {
                int row = row0 + wr * 64 + mt * 16 + kb * 4 + r;
                PS[row * 16 + blockIdx.x * 2 + wc] = p;
            }
        }
    }
}

// ---------- attention weights per span ----------
__global__ __launch_bounds__(256) void k_attn(const float* __restrict__ hs,
                                              const int* __restrict__ starts,
                                              const int* __restrict__ ends,
                                              float* __restrict__ attn) {
    int s = blockIdx.x * 256 + threadIdx.x;
    if (s >= NS) return;
    int st = starts[s], en = ends[s];
    int width = en - st + 1;
    float v[MAXW];
    float mx = -3.0e38f;
    #pragma unroll
    for (int w = 0; w < MAXW; ++w) {
        int idx = st + w; if (idx > NW - 1) idx = NW - 1;
        float x = hs[idx];
        v[w] = (w < width) ? x : -3.0e38f;
        mx = fmaxf(mx, v[w]);
    }
    float sum = 0.f;
    #pragma unroll
    for (int w = 0; w < MAXW; ++w) { v[w] = expf(v[w] - mx); sum += v[w]; }
    float inv = 1.f / sum;
    #pragma unroll
    for (int w = 0; w < MAXW; ++w) attn[s * 32 + w] = v[w] * inv;
}

// ---------- h1 assembly: gather P rows + attended + bias + relu -> bf16 hi/lo ----------
__global__ __launch_bounds__(256) void k_h1(const float* __restrict__ P,
                                            const float* __restrict__ P4,
                                            const float* __restrict__ attn,
                                            const float* __restrict__ b1,
                                            const int* __restrict__ starts,
                                            const int* __restrict__ ends,
                                            ushort* __restrict__ H1h,
                                            ushort* __restrict__ H1l) {
    int s = blockIdx.x;
    int tid = threadIdx.x;
    if (tid >= 250) return;
    int st = starts[s], en = ends[s];
    int width = en - st + 1;
    const float4* P1r = (const float4*)(P + (size_t)st * FFNN);
    const float4* P2r = (const float4*)(P + (size_t)NW * FFNN + (size_t)en * FFNN);
    const float*  P3  = P + 2 * (size_t)NW * FFNN;
    const float4* P4r = (const float4*)(P4 + (size_t)(width - 1) * FFNN);
    const float4* b1v = (const float4*)b1;
    const float*  ar  = attn + s * 32;
    float4 a = P1r[tid], b = P2r[tid], c = P4r[tid], d = b1v[tid];
    float4 acc = {a.x + b.x + c.x + d.x,
                  a.y + b.y + c.y + d.y,
                  a.z + b.z + c.z + d.z,
                  a.w + b.w + c.w + d.w};
    for (int w = 0; w < width; ++w) {
        float aw = ar[w];
        float4 p3 = ((const float4*)(P3 + (size_t)(st + w) * FFNN))[tid];
        acc.x = fmaf(aw, p3.x, acc.x);
        acc.y = fmaf(aw, p3.y, acc.y);
        acc.z = fmaf(aw, p3.z, acc.z);
        acc.w = fmaf(aw, p3.w, acc.w);
    }
    float rv[4] = {fmaxf(acc.x, 0.f), fmaxf(acc.y, 0.f), fmaxf(acc.z, 0.f), fmaxf(acc.w, 0.f)};
    ushort4 hi, lo;
    ushort* hp = (ushort*)&hi;
    ushort* lp = (ushort*)&lo;
    #pragma unroll
    for (int j = 0; j < 4; ++j) {
        ushort h = f2b(rv[j]);
        float r = rv[j] - b2f(h);
        hp[j] = h;
        lp[j] = f2b(r);
    }
    *(ushort4*)(H1h + (size_t)s * FFNN + tid * 4) = hi;
    *(ushort4*)(H1l + (size_t)s * FFNN + tid * 4) = lo;
}

// ---------- final score: sum 16 partials + b3 ----------
__global__ __launch_bounds__(256) void k_score2(const float* __restrict__ PS,
                                                const float* __restrict__ b3,
                                                float* __restrict__ out) {
    int r = blockIdx.x * 256 + threadIdx.x;
    if (r >= NS) return;
    float s = 0.f;
    #pragma unroll
    for (int b = 0; b < 16; ++b) s += PS[r * 16 + b];
    out[r] = s + b3[0];
}

// ---------- exact descending argsort; emits packed (span,s,e) per rank ----------
__global__ __launch_bounds__(256) void k_rank(const float* __restrict__ scores,
                                              const int* __restrict__ starts,
                                              const int* __restrict__ ends,
                                              unsigned long long* __restrict__ pk) {
    __shared__ unsigned long long tile[256];
    int i = blockIdx.x * 256 + threadIdx.x;
    unsigned u = __float_as_uint(scores[i]);
    unsigned m = (u >> 31) ? ~u : (u | 0x80000000u);
    unsigned long long key = ((unsigned long long)(~m) << 32) | (unsigned)i;
    int rank = 0;
    for (int t = 0; t < NS / 256; ++t) {
        int j = t * 256 + threadIdx.x;
        unsigned uj = __float_as_uint(scores[j]);
        unsigned mj = (uj >> 31) ? ~uj : (uj | 0x80000000u);
        tile[threadIdx.x] = ((unsigned long long)(~mj) << 32) | (unsigned)j;
        __syncthreads();
        #pragma unroll 8
        for (int q = 0; q < 256; ++q) rank += (tile[q] < key);
        __syncthreads();
    }
    int st = starts[i], en = ends[i];
    pk[rank] = ((unsigned long long)(unsigned)i << 32) |
               ((unsigned)st << 16) | (unsigned)en;
}

// ---------- greedy crossing-suppression scan: O(1) cross-check state ----------
// mxs[p] = max start among accepted spans straddling gap p->p+1 (s'<=p<e')
// mne[p] = min end   among accepted spans with s''<p<=e''
// mxe[p] = max end   among accepted spans starting exactly at p (dup check)
// cross1 <=> mxs[e] > s ; cross2 <=> mne[s] < e  (window-any collapsed to O(1))
__global__ __launch_bounds__(64) void k_scan(const unsigned long long* __restrict__ pk,
                                             int top, float* __restrict__ out_idx) {
    __shared__ int mxs[NW];
    __shared__ int mne[NW];
    __shared__ int mxe[NW];
    __shared__ int sel[512];
    __shared__ int selkey[512];
    int lane = threadIdx.x;
    unsigned long long lower = (1ull << lane) - 1ull;
    for (int p = lane; p < NW; p += 64) { mxs[p] = -1; mne[p] = NW; mxe[p] = -1; }
    for (int r = lane; r < top; r += 64) { sel[r] = -1; selkey[r] = NW * NW; }
    __syncthreads();
    int count = 0;
    unsigned long long pc = pk[lane];
    for (int c = 0; c < NS / 64; ++c) {
        unsigned long long pn = 0;
        if (c + 1 < NS / 64) pn = pk[(c + 1) * 64 + lane];   // prefetch
        int span = (int)(pc >> 32);
        int s = (int)((pc >> 16) & 0xFFFF);
        int e = (int)(pc & 0xFFFF);
        int bad = (mxs[e] > s) | (mne[s] < e);
        int g = mxe[s];
        bool gdup = (g == e), ggt = (g > e);
        unsigned long long M = __ballot(!bad);
        if (M) {
            // pairwise masks vs candidate lanes
            unsigned long long conf = 0, eqm = 0, gtm = 0;
            unsigned long long t = M;
            while (t) {
                int i = __builtin_ctzll(t); t &= t - 1;
                int si = __builtin_amdgcn_readlane(s, i);
                int ei = __builtin_amdgcn_readlane(e, i);
                unsigned long long bit = 1ull << i;
                if (((si > s) & (si <= e) & (ei > e)) |
                    ((ei >= s) & (ei < e) & (si < s))) conf |= bit;
                if (si == s) { if (ei == e) eqm |= bit; else if (ei > e) gtm |= bit; }
            }
            // ballot-only sequential-order resolution
            unsigned long long pending = M, committed = 0;
            while (pending) {
                bool mine = (pending >> lane) & 1;
                unsigned long long relv = (conf | eqm | gtm) & lower;
                bool ready = mine && ((pending & relv) == 0ull);
                unsigned long long cb = committed & lower;
                bool rej = (cb & conf) != 0ull;
                bool gt_any = ggt || ((cb & gtm) != 0ull);
                bool eq_any = gdup || ((cb & eqm) != 0ull);
                bool acc_now = ready && !rej && !(eq_any && !gt_any);
                committed |= __ballot(acc_now);
                pending &= ~__ballot(ready);
            }
            // cap at top
            int allowed = top - count;
            while (__popcll(committed) > allowed)
                committed &= ~(1ull << (63 - __builtin_clzll(committed)));
            if ((committed >> lane) & 1) {
                int pos = count + __popcll(committed & lower);
                sel[pos] = span;
                selkey[pos] = s * NW + e;
            }
            // state updates: range-update mxs/mne, point-update mxe
            unsigned long long cb2 = committed;
            while (cb2) {
                int i = __builtin_ctzll(cb2); cb2 &= cb2 - 1;
                int si = __builtin_amdgcn_readlane(s, i);
                int ei = __builtin_amdgcn_readlane(e, i);
                if (lane == 0) atomicMax(&mxe[si], ei);
                int wv = ei - si;
                if (lane < wv) {
                    atomicMax(&mxs[si + lane], si);
                    atomicMin(&mne[si + 1 + lane], ei);
                }
            }
            count += __popcll(committed);
        }
        __syncthreads();
        if (count >= top) break;
        pc = pn;
    }
    // stable rank-sort of sel[0..top) by selkey (captured at commit)
    for (int r = lane; r < top; r += 64) {
        int kr = selkey[r];
        int rank = 0;
        for (int q = 0; q < top; ++q) {
            int kq = selkey[q];
            rank += (kq < kr) || (kq == kr && q < r);
        }
        out_idx[rank] = (float)sel[r];
    }
}

extern "C" void kernel_launch(void* const* d_in, const int* in_sizes, int n_in,
                              void* d_out, int out_size, void* d_ws, size_t ws_size,
                              hipStream_t stream) {
    const float* doc = (const float*)d_in[0];
    const float* wwe = (const float*)d_in[1];
    const float* wh  = (const float*)d_in[2];
    const float* bh  = (const float*)d_in[3];
    const float* W1  = (const float*)d_in[4];
    const float* b1  = (const float*)d_in[5];
    const float* W2  = (const float*)d_in[6];
    const float* b2  = (const float*)d_in[7];
    const float* W3  = (const float*)d_in[8];
    const float* b3  = (const float*)d_in[9];
    const int* starts = (const int*)d_in[10];
    const int* ends   = (const int*)d_in[11];
    int top = out_size - NS;                 // 409

    float* ws  = (float*)d_ws;
    float* P   = ws + O_P;
    float* P4  = ws + O_P4;
    float* HS  = ws + O_HS;
    float* ATT = ws + O_ATT;
    float* PS  = ws + O_PS;
    float* H1R = ws + O_H1R;
    ushort* H1H = (ushort*)H1R;
    ushort* H1L = (ushort*)(H1R + 4096000);
    ushort* W1TH = (ushort*)H1R;
    ushort* W1TL = (ushort*)(H1R + 1179648);
    ushort* DOCH = (ushort*)(H1R + 2359296);
    ushort* DOCL = (ushort*)(H1R + 2752512);
    ushort* W2TH = (ushort*)ws;
    ushort* W2TL = (ushort*)(ws + 512000);
    unsigned long long* PK = (unsigned long long*)H1R;   // dead after k_gemm2m
    float* outs = (float*)d_out;

    k_head<<<NW / 4, 256, 0, stream>>>(doc, wh, bh, HS);
    k_p4<<<(30 * FFNN + 255) / 256, 256, 0, stream>>>(wwe, W1, P4);

    k_split<<<(NW * D + 255) / 256, 256, 0, stream>>>(doc, DOCH, DOCL, NW * D);
    {
        dim3 g(24, 32, 3), b(32, 8);
        k_tw1<<<g, b, 0, stream>>>(W1, W1TH, W1TL);
    }
    {
        dim3 g(8, 8, 3);
        k_gemmPm<<<g, 256, 0, stream>>>(DOCH, DOCL, W1TH, W1TL, P);
    }

    k_attn<<<NS / 256, 256, 0, stream>>>(HS, starts, ends, ATT);
    k_h1<<<NS, 256, 0, stream>>>(P, P4, ATT, b1, starts, ends, H1H, H1L);

    {
        dim3 g(32, 32), b(32, 8);
        k_tw2<<<g, b, 0, stream>>>(W2, W2TH, W2TL);
    }
    {
        dim3 g(8, NS / 128);
        k_gemm2m<<<g, 256, 0, stream>>>(H1H, H1L, W2TH, W2TL, b2, W3, PS);
    }

    k_score2<<<NS / 256, 256, 0, stream>>>(PS, b3, outs);
    k_rank<<<NS / 256, 256, 0, stream>>>(outs, starts, ends, PK);
    k_scan<<<1, 64, 0, stream>>>(PK, top, outs + NS);
}

// Round 7
// 514.965 us; speedup vs baseline: 1.0077x; 1.0077x over previous
//
#include <hip/hip_runtime.h>
#include <hip/hip_bf16.h>
#include <stdint.h>

#define NW   1024
#define D    768
#define NS   8192
#define MAXW 30
#define FFNN 1000
#define FEAT 20

typedef __attribute__((ext_vector_type(8))) short bf16x8;
typedef __attribute__((ext_vector_type(4))) float f32x4;
#define MFMA16 __builtin_amdgcn_mfma_f32_16x16x32_bf16

// ws layout (float-slot offsets)
#define O_P    0                          // 3*1024*1000 fp32 P1,P2,P3
#define O_P4   3072000                    // 30*1000
#define O_HS   3102000                    // 1024
#define O_ATT  3103024                    // 8192*32
#define O_PS   3365168                    // 8192*16
#define O_H1R  3504432                    // H1 hi/lo bf16; later pk[8192] u64

__device__ inline ushort f2b(float v) {
    __hip_bfloat16 b = __float2bfloat16(v);
    return *(ushort*)&b;
}
__device__ inline float b2f(ushort u) {
    __hip_bfloat16 b = *(__hip_bfloat16*)&u;
    return __bfloat162float(b);
}

// ---------- head scores ----------
__global__ __launch_bounds__(256) void k_head(const float* __restrict__ doc,
                                              const float* __restrict__ wh,
                                              const float* __restrict__ bh,
                                              float* __restrict__ hs) {
    int wid = threadIdx.x >> 6, lane = threadIdx.x & 63;
    int word = blockIdx.x * 4 + wid;
    const float* row = doc + word * D;
    float acc = 0.f;
    for (int d = lane; d < D; d += 64) acc += row[d] * wh[d];
    #pragma unroll
    for (int o = 32; o; o >>= 1) acc += __shfl_down(acc, o);
    if (lane == 0) hs[word] = acc + bh[0];
}

// ---------- P4 = w_width_emb @ W1[1536:1556,:] ----------
__global__ __launch_bounds__(256) void k_p4(const float* __restrict__ wwe,
                                            const float* __restrict__ W1,
                                            float* __restrict__ P4) {
    int o = blockIdx.x * 256 + threadIdx.x;
    if (o >= 30 * FFNN) return;
    int wi = o / FFNN, j = o - wi * FFNN;
    float acc = 0.f;
    #pragma unroll
    for (int f = 0; f < FEAT; ++f) acc += wwe[wi * FEAT + f] * W1[(1536 + f) * FFNN + j];
    P4[o] = acc;
}

// ---------- split fp32 -> bf16 hi/lo ----------
__global__ __launch_bounds__(256) void k_split(const float* __restrict__ src,
                                               ushort* __restrict__ h,
                                               ushort* __restrict__ l, int n) {
    int i = blockIdx.x * 256 + threadIdx.x;
    if (i >= n) return;
    float v = src[i];
    ushort hi = f2b(v);
    float r = v - b2f(hi);
    h[i] = hi;
    l[i] = f2b(r);
}

// ---------- W1 slices: transpose + split -> W1T[z][1024 n][768 k] hi/lo ----------
__global__ void k_tw1(const float* __restrict__ W1,
                      ushort* __restrict__ TH, ushort* __restrict__ TL) {
    __shared__ float tile[32][33];
    int tx = threadIdx.x, ty = threadIdx.y;
    int k0 = blockIdx.x * 32, n0 = blockIdx.y * 32, z = blockIdx.z;
    int roff = (z == 0) ? 0 : (z == 1) ? 768 : 1556;
    #pragma unroll
    for (int i = 0; i < 4; ++i) {
        int kk = ty + i * 8;
        float v = (n0 + tx < FFNN) ? W1[(size_t)(roff + k0 + kk) * FFNN + n0 + tx] : 0.f;
        tile[kk][tx] = v;
    }
    __syncthreads();
    #pragma unroll
    for (int i = 0; i < 4; ++i) {
        int nn = ty + i * 8;
        float v = tile[tx][nn];
        ushort hi = f2b(v);
        float r = v - b2f(hi);
        size_t o = (size_t)z * 1024 * D + (size_t)(n0 + nn) * D + k0 + tx;
        TH[o] = hi;
        TL[o] = f2b(r);
    }
}

// ---------- W2: transpose + split -> W2T[1024 n][1000 k] hi/lo ----------
__global__ void k_tw2(const float* __restrict__ W2,
                      ushort* __restrict__ TH, ushort* __restrict__ TL) {
    __shared__ float tile[32][33];
    int tx = threadIdx.x, ty = threadIdx.y;
    int k0 = blockIdx.x * 32, n0 = blockIdx.y * 32;
    #pragma unroll
    for (int i = 0; i < 4; ++i) {
        int kk = ty + i * 8;
        float v = (k0 + kk < FFNN && n0 + tx < FFNN)
                    ? W2[(size_t)(k0 + kk) * FFNN + n0 + tx] : 0.f;
        tile[kk][tx] = v;
    }
    __syncthreads();
    #pragma unroll
    for (int i = 0; i < 4; ++i) {
        int nn = ty + i * 8;
        int k = k0 + tx;
        if (k < FFNN) {
            float v = tile[tx][nn];
            ushort hi = f2b(v);
            float r = v - b2f(hi);
            size_t o = (size_t)(n0 + nn) * FFNN + k;
            TH[o] = hi;
            TL[o] = f2b(r);
        }
    }
}

// ---------- MFMA GEMM: P[z] = doc @ W1slice  (split-bf16 3-term, 128x128 tile) ----------
__global__ __launch_bounds__(256) void k_gemmPm(const ushort* __restrict__ Ah_g,
                                                const ushort* __restrict__ Al_g,
                                                const ushort* __restrict__ Bh_g,
                                                const ushort* __restrict__ Bl_g,
                                                float* __restrict__ Pout) {
    __shared__ ushort Ah[128][40], Al[128][40], Bh[128][40], Bl[128][40];
    int tid = threadIdx.x;
    int row0 = blockIdx.y * 128, col0 = blockIdx.x * 128;
    size_t zoff = (size_t)blockIdx.z * 1024 * D;
    const ushort* Bh_z = Bh_g + zoff;
    const ushort* Bl_z = Bl_g + zoff;
    float* C = Pout + (size_t)blockIdx.z * NW * FFNN;
    int w = tid >> 6, l = tid & 63;
    int wr = w >> 1, wc = w & 1;
    int fr = l & 15, kb = l >> 4;
    f32x4 acc[4][4] = {};
    for (int kt = 0; kt < D; kt += 32) {
        #pragma unroll
        for (int i = 0; i < 2; ++i) {
            int cid = tid + i * 256;
            int r = cid >> 2, kc = cid & 3;
            int kg = kt + kc * 8;
            uint4 a0 = *(const uint4*)(Ah_g + (size_t)(row0 + r) * D + kg);
            uint4 a1 = *(const uint4*)(Al_g + (size_t)(row0 + r) * D + kg);
            uint4 b0 = *(const uint4*)(Bh_z + (size_t)(col0 + r) * D + kg);
            uint4 b1 = *(const uint4*)(Bl_z + (size_t)(col0 + r) * D + kg);
            *(uint4*)&Ah[r][kc * 8] = a0;
            *(uint4*)&Al[r][kc * 8] = a1;
            *(uint4*)&Bh[r][kc * 8] = b0;
            *(uint4*)&Bl[r][kc * 8] = b1;
        }
        __syncthreads();
        bf16x8 af[4], alf[4], bfr[4], blf[4];
        #pragma unroll
        for (int mt = 0; mt < 4; ++mt) {
            int r = wr * 64 + mt * 16 + fr;
            af[mt]  = *(const bf16x8*)&Ah[r][kb * 8];
            alf[mt] = *(const bf16x8*)&Al[r][kb * 8];
        }
        #pragma unroll
        for (int nt = 0; nt < 4; ++nt) {
            int c = wc * 64 + nt * 16 + fr;
            bfr[nt] = *(const bf16x8*)&Bh[c][kb * 8];
            blf[nt] = *(const bf16x8*)&Bl[c][kb * 8];
        }
        #pragma unroll
        for (int mt = 0; mt < 4; ++mt)
            #pragma unroll
            for (int nt = 0; nt < 4; ++nt) {
                acc[mt][nt] = MFMA16(af[mt], bfr[nt], acc[mt][nt], 0, 0, 0);
                acc[mt][nt] = MFMA16(af[mt], blf[nt], acc[mt][nt], 0, 0, 0);
                acc[mt][nt] = MFMA16(alf[mt], bfr[nt], acc[mt][nt], 0, 0, 0);
            }
        __syncthreads();
    }
    #pragma unroll
    for (int mt = 0; mt < 4; ++mt)
        #pragma unroll
        for (int nt = 0; nt < 4; ++nt)
            #pragma unroll
            for (int r = 0; r < 4; ++r) {
                int row = row0 + wr * 64 + mt * 16 + kb * 4 + r;
                int col = col0 + wc * 64 + nt * 16 + fr;
                if (col < FFNN) C[(size_t)row * FFNN + col] = acc[mt][nt][r];
            }
}

// ---------- MFMA GEMM2 fused: relu(H1@W2+b2).W3 -> PS  (split-bf16, 128x128) ----------
__global__ __launch_bounds__(256) void k_gemm2m(const ushort* __restrict__ Ah_g,
                                                const ushort* __restrict__ Al_g,
                                                const ushort* __restrict__ Bh_g,
                                                const ushort* __restrict__ Bl_g,
                                                const float* __restrict__ b2,
                                                const float* __restrict__ W3,
                                                float* __restrict__ PS) {
    __shared__ ushort Ah[128][40], Al[128][40], Bh[128][40], Bl[128][40];
    int tid = threadIdx.x;
    int row0 = blockIdx.y * 128, col0 = blockIdx.x * 128;
    int w = tid >> 6, l = tid & 63;
    int wr = w >> 1, wc = w & 1;
    int fr = l & 15, kb = l >> 4;
    f32x4 acc[4][4] = {};
    for (int kt = 0; kt < FFNN; kt += 32) {
        #pragma unroll
        for (int i = 0; i < 2; ++i) {
            int cid = tid + i * 256;
            int r = cid >> 2, kc = cid & 3;
            int kg = kt + kc * 8;
            bool v = (kg + 7) < FFNN;
            uint4 z = make_uint4(0, 0, 0, 0);
            uint4 a0 = v ? *(const uint4*)(Ah_g + (size_t)(row0 + r) * FFNN + kg) : z;
            uint4 a1 = v ? *(const uint4*)(Al_g + (size_t)(row0 + r) * FFNN + kg) : z;
            uint4 b0 = v ? *(const uint4*)(Bh_g + (size_t)(col0 + r) * FFNN + kg) : z;
            uint4 b1 = v ? *(const uint4*)(Bl_g + (size_t)(col0 + r) * FFNN + kg) : z;
            *(uint4*)&Ah[r][kc * 8] = a0;
            *(uint4*)&Al[r][kc * 8] = a1;
            *(uint4*)&Bh[r][kc * 8] = b0;
            *(uint4*)&Bl[r][kc * 8] = b1;
        }
        __syncthreads();
        bf16x8 af[4], alf[4], bfr[4], blf[4];
        #pragma unroll
        for (int mt = 0; mt < 4; ++mt) {
            int r = wr * 64 + mt * 16 + fr;
            af[mt]  = *(const bf16x8*)&Ah[r][kb * 8];
            alf[mt] = *(const bf16x8*)&Al[r][kb * 8];
        }
        #pragma unroll
        for (int nt = 0; nt < 4; ++nt) {
            int c = wc * 64 + nt * 16 + fr;
            bfr[nt] = *(const bf16x8*)&Bh[c][kb * 8];
            blf[nt] = *(const bf16x8*)&Bl[c][kb * 8];
        }
        #pragma unroll
        for (int mt = 0; mt < 4; ++mt)
            #pragma unroll
            for (int nt = 0; nt < 4; ++nt) {
                acc[mt][nt] = MFMA16(af[mt], bfr[nt], acc[mt][nt], 0, 0, 0);
                acc[mt][nt] = MFMA16(af[mt], blf[nt], acc[mt][nt], 0, 0, 0);
                acc[mt][nt] = MFMA16(alf[mt], bfr[nt], acc[mt][nt], 0, 0, 0);
            }
        __syncthreads();
    }
    float w3v[4], b2v[4];
    #pragma unroll
    for (int nt = 0; nt < 4; ++nt) {
        int col = col0 + wc * 64 + nt * 16 + fr;
        bool cv = col < FFNN;
        w3v[nt] = cv ? W3[col] : 0.f;
        b2v[nt] = cv ? b2[col] : 0.f;
    }
    #pragma unroll
    for (int mt = 0; mt < 4; ++mt) {
        #pragma unroll
        for (int r = 0; r < 4; ++r) {
            float p = 0.f;
            #pragma unroll
            for (int nt = 0; nt < 4; ++nt) {
                float v = fmaxf(acc[mt][nt][r] + b2v[nt], 0.f);
                p = fmaf(v, w3v[nt], p);
            }
            p += __shfl_xor(p, 1);
            p += __shfl_xor(p, 2);
            p += __shfl_xor(p, 4);
            p += __shfl_xor(p, 8);
            if (fr == 0) {
                int row = row0 + wr * 64 + mt * 16 + kb * 4 + r;
                PS[row * 16 + blockIdx.x * 2 + wc] = p;
            }
        }
    }
}

// ---------- attention weights per span ----------
__global__ __launch_bounds__(256) void k_attn(const float* __restrict__ hs,
                                              const int* __restrict__ starts,
                                              const int* __restrict__ ends,
                                              float* __restrict__ attn) {
    int s = blockIdx.x * 256 + threadIdx.x;
    if (s >= NS) return;
    int st = starts[s], en = ends[s];
    int width = en - st + 1;
    float v[MAXW];
    float mx = -3.0e38f;
    #pragma unroll
    for (int w = 0; w < MAXW; ++w) {
        int idx = st + w; if (idx > NW - 1) idx = NW - 1;
        float x = hs[idx];
        v[w] = (w < width) ? x : -3.0e38f;
        mx = fmaxf(mx, v[w]);
    }
    float sum = 0.f;
    #pragma unroll
    for (int w = 0; w < MAXW; ++w) { v[w] = expf(v[w] - mx); sum += v[w]; }
    float inv = 1.f / sum;
    #pragma unroll
    for (int w = 0; w < MAXW; ++w) attn[s * 32 + w] = v[w] * inv;
}

// ---------- h1 assembly: gather P rows + attended + bias + relu -> bf16 hi/lo ----------
__global__ __launch_bounds__(256) void k_h1(const float* __restrict__ P,
                                            const float* __restrict__ P4,
                                            const float* __restrict__ attn,
                                            const float* __restrict__ b1,
                                            const int* __restrict__ starts,
                                            const int* __restrict__ ends,
                                            ushort* __restrict__ H1h,
                                            ushort* __restrict__ H1l) {
    int s = blockIdx.x;
    int tid = threadIdx.x;
    if (tid >= 250) return;
    int st = starts[s], en = ends[s];
    int width = en - st + 1;
    const float4* P1r = (const float4*)(P + (size_t)st * FFNN);
    const float4* P2r = (const float4*)(P + (size_t)NW * FFNN + (size_t)en * FFNN);
    const float*  P3  = P + 2 * (size_t)NW * FFNN;
    const float4* P4r = (const float4*)(P4 + (size_t)(width - 1) * FFNN);
    const float4* b1v = (const float4*)b1;
    const float*  ar  = attn + s * 32;
    float4 a = P1r[tid], b = P2r[tid], c = P4r[tid], d = b1v[tid];
    float4 acc = {a.x + b.x + c.x + d.x,
                  a.y + b.y + c.y + d.y,
                  a.z + b.z + c.z + d.z,
                  a.w + b.w + c.w + d.w};
    for (int w = 0; w < width; ++w) {
        float aw = ar[w];
        float4 p3 = ((const float4*)(P3 + (size_t)(st + w) * FFNN))[tid];
        acc.x = fmaf(aw, p3.x, acc.x);
        acc.y = fmaf(aw, p3.y, acc.y);
        acc.z = fmaf(aw, p3.z, acc.z);
        acc.w = fmaf(aw, p3.w, acc.w);
    }
    float rv[4] = {fmaxf(acc.x, 0.f), fmaxf(acc.y, 0.f), fmaxf(acc.z, 0.f), fmaxf(acc.w, 0.f)};
    ushort4 hi, lo;
    ushort* hp = (ushort*)&hi;
    ushort* lp = (ushort*)&lo;
    #pragma unroll
    for (int j = 0; j < 4; ++j) {
        ushort h = f2b(rv[j]);
        float r = rv[j] - b2f(h);
        hp[j] = h;
        lp[j] = f2b(r);
    }
    *(ushort4*)(H1h + (size_t)s * FFNN + tid * 4) = hi;
    *(ushort4*)(H1l + (size_t)s * FFNN + tid * 4) = lo;
}

// ---------- final score: sum 16 partials + b3 ----------
__global__ __launch_bounds__(256) void k_score2(const float* __restrict__ PS,
                                                const float* __restrict__ b3,
                                                float* __restrict__ out) {
    int r = blockIdx.x * 256 + threadIdx.x;
    if (r >= NS) return;
    float s = 0.f;
    #pragma unroll
    for (int b = 0; b < 16; ++b) s += PS[r * 16 + b];
    out[r] = s + b3[0];
}

// ---------- exact descending argsort; emits packed (span,s,e) per rank ----------
__global__ __launch_bounds__(256) void k_rank(const float* __restrict__ scores,
                                              const int* __restrict__ starts,
                                              const int* __restrict__ ends,
                                              unsigned long long* __restrict__ pk) {
    __shared__ unsigned long long tile[256];
    int i = blockIdx.x * 256 + threadIdx.x;
    unsigned u = __float_as_uint(scores[i]);
    unsigned m = (u >> 31) ? ~u : (u | 0x80000000u);
    unsigned long long key = ((unsigned long long)(~m) << 32) | (unsigned)i;
    int rank = 0;
    for (int t = 0; t < NS / 256; ++t) {
        int j = t * 256 + threadIdx.x;
        unsigned uj = __float_as_uint(scores[j]);
        unsigned mj = (uj >> 31) ? ~uj : (uj | 0x80000000u);
        tile[threadIdx.x] = ((unsigned long long)(~mj) << 32) | (unsigned)j;
        __syncthreads();
        #pragma unroll 8
        for (int q = 0; q < 256; ++q) rank += (tile[q] < key);
        __syncthreads();
    }
    int st = starts[i], en = ends[i];
    pk[rank] = ((unsigned long long)(unsigned)i << 32) |
               ((unsigned)st << 16) | (unsigned)en;
}

// ---------- greedy crossing-suppression scan ----------
// O(1) global check (mxs/mne/mxe state) + commit-lowest in-chunk resolution:
// serial work scales with ACCEPTS (~409), not candidates (~5800).
// Per accepted (sj,ej): broadcast via readlane; every lane updates its
// conflict/eq/gt flags in-register. Batch-reject conf-dead lanes (monotone);
// lowest pending lane always has final flags (all lower decided).
__global__ __launch_bounds__(64) void k_scan(const unsigned long long* __restrict__ pk,
                                             int top, float* __restrict__ out_idx) {
    __shared__ int mxs[NW];    // max start among accepted straddling gap p->p+1
    __shared__ int mne[NW];    // min end among accepted with s'' < p <= e''
    __shared__ int mxe[NW];    // max end among accepted starting exactly at p
    __shared__ int sel[512];
    __shared__ int selkey[512];
    int lane = threadIdx.x;
    for (int p = lane; p < NW; p += 64) { mxs[p] = -1; mne[p] = NW; mxe[p] = -1; }
    for (int r = lane; r < top; r += 64) { sel[r] = -1; selkey[r] = NW * NW; }
    __syncthreads();
    int count = 0;
    unsigned long long pc = pk[lane];
    for (int c = 0; c < NS / 64 && count < top; ++c) {
        unsigned long long pn = 0;
        if (c + 1 < NS / 64) pn = pk[(c + 1) * 64 + lane];   // prefetch
        int span = (int)(pc >> 32);
        int s = (int)((pc >> 16) & 0xFFFF);
        int e = (int)(pc & 0xFFFF);
        int bad = (mxs[e] > s) | (mne[s] < e);   // exact global cross check
        int g = mxe[s];
        bool rej = false;            // conflict vs in-chunk committed (monotone)
        bool eqf = (g == e);         // some same-start accepted with equal end
        bool gtf = (g > e);          // some same-start accepted with larger end
        unsigned long long pending = __ballot(!bad);
        while (pending) {
            pending &= ~__ballot(rej);          // batch-reject (conf is monotone)
            if (!pending) break;
            int j0 = __builtin_ctzll(pending);  // lowest pending: flags final
            pending &= pending - 1;
            bool acc = !rej && !(eqf && !gtf);
            bool j0acc = (__ballot(acc) >> j0) & 1;
            if (j0acc) {
                int sj = __builtin_amdgcn_readlane(s, j0);
                int ej = __builtin_amdgcn_readlane(e, j0);
                int spj = __builtin_amdgcn_readlane(span, j0);
                if (lane == 0) {
                    sel[count] = spj;
                    selkey[count] = sj * NW + ej;
                    if (ej > mxe[sj]) mxe[sj] = ej;
                }
                if (lane < ej - sj) {
                    atomicMax(&mxs[sj + lane], sj);
                    atomicMin(&mne[sj + 1 + lane], ej);
                }
                rej = rej | (((sj > s) & (sj <= e) & (ej > e)) |
                             ((ej >= s) & (ej < e) & (sj < s)));
                if (sj == s) { eqf = eqf | (ej == e); gtf = gtf | (ej > e); }
                ++count;
                if (count >= top) break;
            }
        }
        __syncthreads();
        pc = pn;
    }
    // stable rank-sort of sel[0..top) by selkey (captured at commit)
    for (int r = lane; r < top; r += 64) {
        int kr = selkey[r];
        int rank = 0;
        for (int q = 0; q < top; ++q) {
            int kq = selkey[q];
            rank += (kq < kr) || (kq == kr && q < r);
        }
        out_idx[rank] = (float)sel[r];
    }
}

extern "C" void kernel_launch(void* const* d_in, const int* in_sizes, int n_in,
                              void* d_out, int out_size, void* d_ws, size_t ws_size,
                              hipStream_t stream) {
    const float* doc = (const float*)d_in[0];
    const float* wwe = (const float*)d_in[1];
    const float* wh  = (const float*)d_in[2];
    const float* bh  = (const float*)d_in[3];
    const float* W1  = (const float*)d_in[4];
    const float* b1  = (const float*)d_in[5];
    const float* W2  = (const float*)d_in[6];
    const float* b2  = (const float*)d_in[7];
    const float* W3  = (const float*)d_in[8];
    const float* b3  = (const float*)d_in[9];
    const int* starts = (const int*)d_in[10];
    const int* ends   = (const int*)d_in[11];
    int top = out_size - NS;                 // 409

    float* ws  = (float*)d_ws;
    float* P   = ws + O_P;
    float* P4  = ws + O_P4;
    float* HS  = ws + O_HS;
    float* ATT = ws + O_ATT;
    float* PS  = ws + O_PS;
    float* H1R = ws + O_H1R;
    ushort* H1H = (ushort*)H1R;
    ushort* H1L = (ushort*)(H1R + 4096000);
    ushort* W1TH = (ushort*)H1R;
    ushort* W1TL = (ushort*)(H1R + 1179648);
    ushort* DOCH = (ushort*)(H1R + 2359296);
    ushort* DOCL = (ushort*)(H1R + 2752512);
    ushort* W2TH = (ushort*)ws;
    ushort* W2TL = (ushort*)(ws + 512000);
    unsigned long long* PK = (unsigned long long*)H1R;   // dead after k_gemm2m
    float* outs = (float*)d_out;

    k_head<<<NW / 4, 256, 0, stream>>>(doc, wh, bh, HS);
    k_p4<<<(30 * FFNN + 255) / 256, 256, 0, stream>>>(wwe, W1, P4);

    k_split<<<(NW * D + 255) / 256, 256, 0, stream>>>(doc, DOCH, DOCL, NW * D);
    {
        dim3 g(24, 32, 3), b(32, 8);
        k_tw1<<<g, b, 0, stream>>>(W1, W1TH, W1TL);
    }
    {
        dim3 g(8, 8, 3);
        k_gemmPm<<<g, 256, 0, stream>>>(DOCH, DOCL, W1TH, W1TL, P);
    }

    k_attn<<<NS / 256, 256, 0, stream>>>(HS, starts, ends, ATT);
    k_h1<<<NS, 256, 0, stream>>>(P, P4, ATT, b1, starts, ends, H1H, H1L);

    {
        dim3 g(32, 32), b(32, 8);
        k_tw2<<<g, b, 0, stream>>>(W2, W2TH, W2TL);
    }
    {
        dim3 g(8, NS / 128);
        k_gemm2m<<<g, 256, 0, stream>>>(H1H, H1L, W2TH, W2TL, b2, W3, PS);
    }

    k_score2<<<NS / 256, 256, 0, stream>>>(PS, b3, outs);
    k_rank<<<NS / 256, 256, 0, stream>>>(outs, starts, ends, PK);
    k_scan<<<1, 64, 0, stream>>>(PK, top, outs + NS);
}